// Round 5
// baseline (98.664 us; speedup 1.0000x reference)
//
#include <hip/hip_runtime.h>
#include <hip/hip_bf16.h>

typedef __attribute__((ext_vector_type(4))) _Float16 f16x4;
typedef __attribute__((ext_vector_type(8))) _Float16 f16x8;
typedef __attribute__((ext_vector_type(4))) float f32x4;

#define B_ 8
#define N_ 4096
#define C_ 64
#define CQ_ 32
#define SPLIT 4
#define KEYS (N_ / SPLIT)
#define NC (KEYS / 32)   // 32-key chunks per block
#define QB 128           // queries per block (4 waves x 32)

#define L2E_ 1.4426950408889634f
#define LOG2L_ 0.5287663729448977f

// ---------------- projection kernel v5 ----------------
// grid: B*(N/64)=512 blocks, 512 threads (8 waves). wave=role, lane=pixel.
// qh = q*c1 fp16 [B][N][32]; kh = k fp16 [B][N][32];
// vfrag = v fp16 in MFMA-fragment order [B][N/32][64ch][lg:4][e:8]
//   where key-within-32  kk -> lg=(kk&15)>>2, e=(kk&3)+4*(kk>>4)
// nqs = log2(log2e) - |q|^2*cdL ; nks = -|k|^2*cdL
__global__ __launch_bounds__(512) void proj_kernel(
    const float* __restrict__ x,
    const float* __restrict__ Wq, const float* __restrict__ bq,
    const float* __restrict__ Wk, const float* __restrict__ bk,
    const float* __restrict__ Wv, const float* __restrict__ bv,
    const float* __restrict__ sigp,
    _Float16* __restrict__ qh, _Float16* __restrict__ kh,
    _Float16* __restrict__ vfrag,
    float* __restrict__ nqs, float* __restrict__ nks)
{
    __shared__ float xs[64][64];   // [channel][pixel]
    __shared__ float sP[4][64];    // q/k norm partials
    const int t = threadIdx.x;
    const int role = __builtin_amdgcn_readfirstlane(t >> 6);
    const int l = t & 63;
    const int b = blockIdx.x >> 6;
    const int n0 = (blockIdx.x & 63) * 64;

    #pragma unroll
    for (int rep = 0; rep < 8; ++rep) {
        const int idx = rep * 512 + t;
        const int c = idx >> 6, pix = idx & 63;
        xs[c][pix] = x[((size_t)b * C_ + c) * N_ + n0 + pix];
    }
    __syncthreads();

    const float* Wr;
    const float* br;
    if (role < 2)      { Wr = Wq + role * 16 * 64;       br = bq + role * 16; }
    else if (role < 4) { Wr = Wk + (role - 2) * 16 * 64; br = bk + (role - 2) * 16; }
    else               { Wr = Wv + (role - 4) * 16 * 64; br = bv + (role - 4) * 16; }

    float acc[16];
    #pragma unroll
    for (int o = 0; o < 16; ++o) acc[o] = br[o];
    #pragma unroll
    for (int c0 = 0; c0 < 64; c0 += 8) {
        float xc[8];
        #pragma unroll
        for (int dc = 0; dc < 8; ++dc) xc[dc] = xs[c0 + dc][l];
        #pragma unroll
        for (int o = 0; o < 16; ++o) {
            #pragma unroll
            for (int dc = 0; dc < 8; ++dc)
                acc[o] = fmaf(Wr[o * 64 + c0 + dc], xc[dc], acc[o]);
        }
    }

    const float sv = sigp[0];
    const float cdL = 0.7213475204444817f / (sv * sv);  // (log2e/2)/sigma^2
    const float c1 = 2.0f * cdL;                        // log2e/sigma^2

    const int n = n0 + l;
    if (role < 4) {
        float s = 0.f;
        #pragma unroll
        for (int o = 0; o < 16; ++o) s = fmaf(acc[o], acc[o], s);
        sP[role][l] = s;
        const bool isq = (role < 2);
        if (isq) {
            #pragma unroll
            for (int o = 0; o < 16; ++o) acc[o] *= c1;   // pre-scale q by c1
        }
        _Float16* row = (isq ? qh : kh) + ((size_t)b * N_ + n) * CQ_ + (role & 1) * 16;
        #pragma unroll
        for (int j = 0; j < 2; ++j) {
            f16x8 h;
            #pragma unroll
            for (int e = 0; e < 8; ++e) h[e] = (_Float16)acc[j * 8 + e];
            *(f16x8*)(row + j * 8) = h;
        }
    } else {
        // v: fragment-order scatter. kk = n&31; lg=(kk&15)>>2; e=(kk&3)+4*(kk>>4)
        const int o0 = (role - 4) * 16;
        const int t32 = n >> 5;
        const int lgv = (l & 15) >> 2;
        const int ev = (l & 3) + ((l >> 2) & 4);   // (l&3) + 4*((l>>4)&1)
        _Float16* vp = vfrag + (((size_t)b * (N_ / 32) + t32) * 64 + o0) * 32 + lgv * 8 + ev;
        #pragma unroll
        for (int o = 0; o < 16; ++o)
            vp[o * 32] = (_Float16)acc[o];
    }
    __syncthreads();
    if (t < 64)
        nqs[(size_t)b * N_ + n0 + t] = LOG2L_ - (sP[0][t] + sP[1][t]) * cdL;
    else if (t < 128)
        nks[(size_t)b * N_ + n0 + (t - 64)] = -(sP[2][t - 64] + sP[3][t - 64]) * cdL;
}

// ---------------- fused RBF-attention v5: no LDS, no barriers, all L2-direct ----------------
// grid: B*(N/128)*SPLIT = 1024 blocks, 256 threads (4 waves). Wave owns 32 queries,
// block owns KEYS=1024 keys processed in 32-key chunks. K prefetched one chunk ahead.
__global__ __launch_bounds__(256, 4) void attn_kernel(
    const _Float16* __restrict__ qh,
    const _Float16* __restrict__ kh,
    const _Float16* __restrict__ vfrag,
    const float* __restrict__ nqs,
    const float* __restrict__ nks,
    _Float16* __restrict__ opart,
    float* __restrict__ dpart)
{
    const int t = threadIdx.x;
    const int wid = t >> 6;
    const int l = t & 63;
    const int lg = l >> 4;
    const int lm = l & 15;

    const int split = blockIdx.x & (SPLIT - 1);
    const int qblk = (blockIdx.x >> 2) & 31;
    const int b = blockIdx.x >> 7;
    const int qbase = qblk * QB + wid * 32;
    const int k0 = split * KEYS;
    const size_t bN = (size_t)b * N_;

    // Q fragments (two 16-query groups), channels 8*lg..8*lg+7
    const f16x8 qfA = *(const f16x8*)(qh + (bN + qbase + lm) * CQ_ + 8 * lg);
    const f16x8 qfB = *(const f16x8*)(qh + (bN + qbase + 16 + lm) * CQ_ + 8 * lg);
    const float nqA = nqs[bN + qbase + lm];
    const float nqB = nqs[bN + qbase + 16 + lm];

    const _Float16* kbase = kh + (bN + k0 + lm) * CQ_ + 8 * lg;
    const _Float16* vbase = vfrag + (((size_t)b * (N_ / 32) + (k0 >> 5)) * 64 + lm) * 32 + lg * 8;
    const float* nkbase = nks + bN + k0 + lg * 4;

    f32x4 accA[4], accB[4];
    #pragma unroll
    for (int i = 0; i < 4; ++i) {
        accA[i] = (f32x4){0.f, 0.f, 0.f, 0.f};
        accB[i] = (f32x4){0.f, 0.f, 0.f, 0.f};
    }
    float denA = 0.f, denB = 0.f;

    f16x8 k0a, k1a, k0b, k1b;
    // prologue: chunk 0 K
    k0a = *(const f16x8*)(kbase);
    k1a = *(const f16x8*)(kbase + 16 * CQ_);

    #pragma unroll 2
    for (int c = 0; c < NC; ++c) {
        const int m0 = c * 32;
        const f16x8 kc0 = (c & 1) ? k0b : k0a;
        const f16x8 kc1 = (c & 1) ? k1b : k1a;

        // ---- issue this chunk's V + nk loads ----
        f16x8 vf0 = *(const f16x8*)(vbase + ((size_t)c * 64 + 0) * 32);
        f16x8 vf1 = *(const f16x8*)(vbase + ((size_t)c * 64 + 16) * 32);
        f16x8 vf2 = *(const f16x8*)(vbase + ((size_t)c * 64 + 32) * 32);
        f16x8 vf3 = *(const f16x8*)(vbase + ((size_t)c * 64 + 48) * 32);
        const f32x4 n0 = *(const f32x4*)(nkbase + m0);
        const f32x4 n1 = *(const f32x4*)(nkbase + m0 + 16);

        // ---- prefetch next chunk's K ----
        if (c + 1 < NC) {
            if (c & 1) {
                k0a = *(const f16x8*)(kbase + (size_t)(m0 + 32) * CQ_);
                k1a = *(const f16x8*)(kbase + (size_t)(m0 + 48) * CQ_);
            } else {
                k0b = *(const f16x8*)(kbase + (size_t)(m0 + 32) * CQ_);
                k1b = *(const f16x8*)(kbase + (size_t)(m0 + 48) * CQ_);
            }
        }

        // ---- S^T = K Q^T ----
        __builtin_amdgcn_s_setprio(1);
        f32x4 SA0 = __builtin_amdgcn_mfma_f32_16x16x32_f16(kc0, qfA, (f32x4){0.f,0.f,0.f,0.f}, 0, 0, 0);
        f32x4 SB0 = __builtin_amdgcn_mfma_f32_16x16x32_f16(kc0, qfB, (f32x4){0.f,0.f,0.f,0.f}, 0, 0, 0);
        f32x4 SA1 = __builtin_amdgcn_mfma_f32_16x16x32_f16(kc1, qfA, (f32x4){0.f,0.f,0.f,0.f}, 0, 0, 0);
        f32x4 SB1 = __builtin_amdgcn_mfma_f32_16x16x32_f16(kc1, qfB, (f32x4){0.f,0.f,0.f,0.f}, 0, 0, 0);
        __builtin_amdgcn_s_setprio(0);

        // ---- w = exp2(exp2(S + nq + nk)); P fragments; denom ----
        f16x8 paA, paB;
        #pragma unroll
        for (int r = 0; r < 4; ++r) {
            const float wA0 = __builtin_amdgcn_exp2f(__builtin_amdgcn_exp2f(SA0[r] + nqA + n0[r]));
            const float wA1 = __builtin_amdgcn_exp2f(__builtin_amdgcn_exp2f(SA1[r] + nqA + n1[r]));
            const float wB0 = __builtin_amdgcn_exp2f(__builtin_amdgcn_exp2f(SB0[r] + nqB + n0[r]));
            const float wB1 = __builtin_amdgcn_exp2f(__builtin_amdgcn_exp2f(SB1[r] + nqB + n1[r]));
            denA += wA0 + wA1;
            denB += wB0 + wB1;
            paA[r] = (_Float16)wA0; paA[4 + r] = (_Float16)wA1;
            paB[r] = (_Float16)wB0; paB[4 + r] = (_Float16)wB1;
        }

        // ---- O += P V ----
        __builtin_amdgcn_s_setprio(1);
        accA[0] = __builtin_amdgcn_mfma_f32_16x16x32_f16(paA, vf0, accA[0], 0, 0, 0);
        accB[0] = __builtin_amdgcn_mfma_f32_16x16x32_f16(paB, vf0, accB[0], 0, 0, 0);
        accA[1] = __builtin_amdgcn_mfma_f32_16x16x32_f16(paA, vf1, accA[1], 0, 0, 0);
        accB[1] = __builtin_amdgcn_mfma_f32_16x16x32_f16(paB, vf1, accB[1], 0, 0, 0);
        accA[2] = __builtin_amdgcn_mfma_f32_16x16x32_f16(paA, vf2, accA[2], 0, 0, 0);
        accB[2] = __builtin_amdgcn_mfma_f32_16x16x32_f16(paB, vf2, accB[2], 0, 0, 0);
        accA[3] = __builtin_amdgcn_mfma_f32_16x16x32_f16(paA, vf3, accA[3], 0, 0, 0);
        accB[3] = __builtin_amdgcn_mfma_f32_16x16x32_f16(paB, vf3, accB[3], 0, 0, 0);
        __builtin_amdgcn_s_setprio(0);
    }

    // ---- denom: each lane holds keys of its lg group -> reduce over lg ----
    denA += __shfl_xor(denA, 16);
    denA += __shfl_xor(denA, 32);
    denB += __shfl_xor(denB, 16);
    denB += __shfl_xor(denB, 32);

    const size_t obA = ((size_t)split * B_ + b) * N_ + qbase;
    if (l < 16) {
        dpart[obA + lm] = denA;
        dpart[obA + 16 + lm] = denB;
    }
    #pragma unroll
    for (int tc = 0; tc < 4; ++tc) {
        #pragma unroll
        for (int r = 0; r < 4; ++r) {
            opart[(obA + lg * 4 + r) * C_ + tc * 16 + lm] = (_Float16)accA[tc][r];
            opart[(obA + 16 + lg * 4 + r) * C_ + tc * 16 + lm] = (_Float16)accB[tc][r];
        }
    }
}

// ---------------- combine kernel: sum partials, divide, add x ----------------
__global__ __launch_bounds__(256) void combine_kernel(
    const float* __restrict__ x,
    const _Float16* __restrict__ opart,
    const float* __restrict__ dpart,
    float* __restrict__ out)
{
    const int gid = blockIdx.x * 256 + threadIdx.x;
    const int c0 = (gid & 7) * 8;
    const int bn = gid >> 3;

    float den = 0.f;
    #pragma unroll
    for (int s = 0; s < SPLIT; ++s) den += dpart[(size_t)s * B_ * N_ + bn];
    const float rden = 1.0f / den;

    float o[8] = {0.f, 0.f, 0.f, 0.f, 0.f, 0.f, 0.f, 0.f};
    #pragma unroll
    for (int s = 0; s < SPLIT; ++s) {
        const f16x8 h = *(const f16x8*)(opart + (((size_t)s * B_ * N_ + bn) * C_ + c0));
        #pragma unroll
        for (int e = 0; e < 8; ++e) o[e] += (float)h[e];
    }

    const size_t base = (size_t)bn * C_ + c0;
    const f32x4 x0 = *(const f32x4*)(x + base);
    const f32x4 x1 = *(const f32x4*)(x + base + 4);
    f32x4 r0, r1;
    #pragma unroll
    for (int e = 0; e < 4; ++e) {
        r0[e] = x0[e] + o[e] * rden;
        r1[e] = x1[e] + o[e + 4] * rden;
    }
    *(f32x4*)(out + base) = r0;
    *(f32x4*)(out + base + 4) = r1;
}

extern "C" void kernel_launch(void* const* d_in, const int* in_sizes, int n_in,
                              void* d_out, int out_size, void* d_ws, size_t ws_size,
                              hipStream_t stream) {
    const float* x   = (const float*)d_in[0];
    const float* Wq  = (const float*)d_in[1];
    const float* bq  = (const float*)d_in[2];
    const float* Wk  = (const float*)d_in[3];
    const float* bk  = (const float*)d_in[4];
    const float* Wv  = (const float*)d_in[5];
    const float* bv  = (const float*)d_in[6];
    const float* sig = (const float*)d_in[7];
    float* out = (float*)d_out;

    char* ws = (char*)d_ws;
    _Float16* qh    = (_Float16*)(ws);                        // 2 MB   [B][N][32]
    _Float16* kh    = (_Float16*)(ws + (2u << 20));           // 2 MB   [B][N][32]
    _Float16* vfrag = (_Float16*)(ws + (4u << 20));           // 4 MB   [B][N/32][64][32]
    float*   nqs    = (float*)(ws + (8u << 20));              // 128 KB [B][N]
    float*   nks    = (float*)(ws + (8u << 20) + (128u << 10)); // 128 KB
    _Float16* opart = (_Float16*)(ws + (8u << 20) + (256u << 10)); // 16 MB [SPLIT][B][N][64]
    float*   dpart  = (float*)(ws + (24u << 20) + (256u << 10));   // 512 KB [SPLIT][B][N]

    proj_kernel<<<B_ * (N_ / 64), 512, 0, stream>>>(x, Wq, bq, Wk, bk, Wv, bv, sig,
                                                    qh, kh, vfrag, nqs, nks);
    attn_kernel<<<B_ * (N_ / QB) * SPLIT, 256, 0, stream>>>(qh, kh, vfrag, nqs, nks,
                                                            opart, dpart);
    combine_kernel<<<(B_ * N_ * 8) / 256, 256, 0, stream>>>(x, opart, dpart, out);
}

// Round 6
// 83.318 us; speedup vs baseline: 1.1842x; 1.1842x over previous
//
#include <hip/hip_runtime.h>
#include <hip/hip_bf16.h>

typedef __attribute__((ext_vector_type(4))) _Float16 f16x4;
typedef __attribute__((ext_vector_type(8))) _Float16 f16x8;
typedef __attribute__((ext_vector_type(4))) float f32x4;

#define B_ 8
#define N_ 4096
#define C_ 64
#define CQ_ 32
#define SPLIT 4
#define KEYS (N_ / SPLIT)
#define MB 64
#define NT (KEYS / MB)   // 16
#define QB 128           // queries per block (4 waves x 32)

#define L2E_ 1.4426950408889634f
#define LOG2L_ 0.5287663729448977f

__device__ __forceinline__ void async16(void* lds, const void* gsrc) {
    __builtin_amdgcn_global_load_lds(
        (const __attribute__((address_space(1))) unsigned int*)gsrc,
        (__attribute__((address_space(3))) unsigned int*)lds, 16, 0, 0);
}

// ---------------- projection kernel v6 ----------------
// grid: B*(N/64)=512 blocks, 512 threads (8 waves). wave=role, lane=pixel.
// Outputs (fragment/granule-major so attn can glds them linearly):
//   qh   [B][N][32]                         q * c1 (c1 = log2e/sigma^2)
//   khf  [B][N/64][g:4][key:64][8 f16]      K granule-major tiles (4 KB/tile)
//   vhf  [B][N/64][j:2][g:4][ch:64][8 f16]  V fragment tiles (8 KB/tile)
//   nqs  [B][N]                             log2(log2e) - |q|^2*cdL
//   nkf  [B][N/32][kappa:32]                -|k|^2*cdL in fragment (kappa) order
__global__ __launch_bounds__(512) void proj_kernel(
    const float* __restrict__ x,
    const float* __restrict__ Wq, const float* __restrict__ bq,
    const float* __restrict__ Wk, const float* __restrict__ bk,
    const float* __restrict__ Wv, const float* __restrict__ bv,
    const float* __restrict__ sigp,
    _Float16* __restrict__ qh, _Float16* __restrict__ khf,
    _Float16* __restrict__ vhf,
    float* __restrict__ nqs, float* __restrict__ nkf)
{
    __shared__ float xs[64][64];          // [channel][pixel]
    __shared__ float sP[4][64];           // q/k norm partials
    __shared__ _Float16 vtmp[64][72];     // [ch][pixel] fp16, padded
    const int t = threadIdx.x;
    const int role = __builtin_amdgcn_readfirstlane(t >> 6);
    const int l = t & 63;
    const int b = blockIdx.x >> 6;
    const int tile = blockIdx.x & 63;
    const int n0 = tile * 64;

    #pragma unroll
    for (int rep = 0; rep < 8; ++rep) {
        const int idx = rep * 512 + t;
        const int c = idx >> 6, pix = idx & 63;
        xs[c][pix] = x[((size_t)b * C_ + c) * N_ + n0 + pix];
    }
    __syncthreads();

    const float* Wr;
    const float* br;
    if (role < 2)      { Wr = Wq + role * 16 * 64;       br = bq + role * 16; }
    else if (role < 4) { Wr = Wk + (role - 2) * 16 * 64; br = bk + (role - 2) * 16; }
    else               { Wr = Wv + (role - 4) * 16 * 64; br = bv + (role - 4) * 16; }

    float acc[16];
    #pragma unroll
    for (int o = 0; o < 16; ++o) acc[o] = br[o];
    #pragma unroll
    for (int c0 = 0; c0 < 64; c0 += 8) {
        float xc[8];
        #pragma unroll
        for (int dc = 0; dc < 8; ++dc) xc[dc] = xs[c0 + dc][l];
        #pragma unroll
        for (int o = 0; o < 16; ++o) {
            #pragma unroll
            for (int dc = 0; dc < 8; ++dc)
                acc[o] = fmaf(Wr[o * 64 + c0 + dc], xc[dc], acc[o]);
        }
    }

    const float sv = sigp[0];
    const float cdL = 0.7213475204444817f / (sv * sv);  // (log2e/2)/sigma^2
    const float c1 = 2.0f * cdL;                        // log2e/sigma^2
    const int n = n0 + l;

    if (role < 2) {                       // ---- q ----
        float s = 0.f;
        #pragma unroll
        for (int o = 0; o < 16; ++o) s = fmaf(acc[o], acc[o], s);
        sP[role][l] = s;
        _Float16* row = qh + ((size_t)b * N_ + n) * CQ_ + role * 16;
        #pragma unroll
        for (int j = 0; j < 2; ++j) {
            f16x8 h;
            #pragma unroll
            for (int e = 0; e < 8; ++e) h[e] = (_Float16)(acc[j * 8 + e] * c1);
            *(f16x8*)(row + j * 8) = h;
        }
    } else if (role < 4) {                // ---- k: granule-major tile store ----
        float s = 0.f;
        #pragma unroll
        for (int o = 0; o < 16; ++o) s = fmaf(acc[o], acc[o], s);
        sP[role][l] = s;
        const size_t tbase = ((size_t)b * (N_ / 64) + tile) * 4;
        #pragma unroll
        for (int gi = 0; gi < 2; ++gi) {
            const int g = (role - 2) * 2 + gi;
            f16x8 h;
            #pragma unroll
            for (int e = 0; e < 8; ++e) h[e] = (_Float16)acc[gi * 8 + e];
            *(f16x8*)(khf + (tbase + g) * 512 + l * 8) = h;
        }
    } else {                              // ---- v -> LDS transpose buffer ----
        const int o0 = (role - 4) * 16;
        #pragma unroll
        for (int o = 0; o < 16; ++o) vtmp[o0 + o][l] = (_Float16)acc[o];
    }
    __syncthreads();

    // ---- cooperative V fragment store: t -> (j=t>>8, g=(t>>6)&3, ch=t&63) ----
    {
        const int j = t >> 8, g = (t >> 6) & 3, ch = t & 63;
        const int p0 = j * 32 + 4 * g;
        const f16x4 a0 = *(const f16x4*)(&vtmp[ch][p0]);       // e=0..3
        const f16x4 a1 = *(const f16x4*)(&vtmp[ch][p0 + 16]);  // e=4..7
        f16x8 hv;
        #pragma unroll
        for (int e = 0; e < 4; ++e) { hv[e] = a0[e]; hv[4 + e] = a1[e]; }
        *(f16x8*)(vhf + ((size_t)b * (N_ / 64) + tile) * 4096 + t * 8) = hv;
    }
    if (t < 64) {
        nqs[(size_t)b * N_ + n0 + t] = LOG2L_ - (sP[0][t] + sP[1][t]) * cdL;
    } else if (t < 128) {
        const int kk = t - 64;
        const int kap = (((kk & 15) >> 2) << 3) + (kk & 3) + (((kk >> 4) & 1) << 2);
        nkf[((size_t)b * (N_ / 32) + ((n0 + kk) >> 5)) * 32 + kap] =
            -(sP[2][kk] + sP[3][kk]) * cdL;
    }
}

// ---------------- fused RBF-attention v6: glds staging + counted vmcnt ----------------
// grid: B*(N/128)*SPLIT = 1024 blocks, 256 threads (4 waves). Wave owns 32 queries.
// Per tile (64 keys): 1 K-glds + 2 V-glds per wave (prefetch), 4 nk f32x4 per lane.
// Two raw barriers/tile; s_waitcnt vmcnt(7) keeps next tile's loads in flight.
__global__ __launch_bounds__(256, 4) void attn_kernel(
    const _Float16* __restrict__ qh,
    const _Float16* __restrict__ khf,
    const _Float16* __restrict__ vhf,
    const float* __restrict__ nqs,
    const float* __restrict__ nkf,
    _Float16* __restrict__ opart,
    float* __restrict__ dpart)
{
    __shared__ __align__(16) _Float16 Kb[2][2048];   // [g:4][key:64][8]
    __shared__ __align__(16) _Float16 Vb[2][4096];   // [j:2][g:4][ch:64][8]

    const int t = threadIdx.x;
    const int wid = t >> 6;
    const int l = t & 63;
    const int lg = l >> 4;
    const int lm = l & 15;

    const int split = blockIdx.x & (SPLIT - 1);
    const int qblk = (blockIdx.x >> 2) & 31;
    const int b = blockIdx.x >> 7;
    const int qbase = qblk * QB + wid * 32;
    const int k0 = split * KEYS;
    const size_t bN = (size_t)b * N_;

    const f16x8 qfA = *(const f16x8*)(qh + (bN + qbase + lm) * CQ_ + 8 * lg);
    const f16x8 qfB = *(const f16x8*)(qh + (bN + qbase + 16 + lm) * CQ_ + 8 * lg);
    const float nqA = nqs[bN + qbase + lm];
    const float nqB = nqs[bN + qbase + 16 + lm];

    const _Float16* kg = khf + ((size_t)b * (N_ / 64) + (k0 >> 6)) * 2048 + wid * 512 + l * 8;
    const _Float16* vg = vhf + ((size_t)b * (N_ / 64) + (k0 >> 6)) * 4096 + wid * 1024 + l * 8;
    const float* nkg = nkf + ((size_t)b * (N_ / 32) + (k0 >> 5)) * 32 + lg * 8;

    f32x4 accA[4], accB[4], accdA, accdB;
    #pragma unroll
    for (int i = 0; i < 4; ++i) {
        accA[i] = (f32x4){0.f, 0.f, 0.f, 0.f};
        accB[i] = (f32x4){0.f, 0.f, 0.f, 0.f};
    }
    accdA = (f32x4){0.f, 0.f, 0.f, 0.f};
    accdB = (f32x4){0.f, 0.f, 0.f, 0.f};
    f16x8 ones;
    #pragma unroll
    for (int e = 0; e < 8; ++e) ones[e] = (_Float16)1.0f;

    #define ISSUE(TILE, BUF) { \
        async16(&Kb[BUF][wid * 512],        kg + (size_t)(TILE) * 2048); \
        async16(&Vb[BUF][wid * 1024],       vg + (size_t)(TILE) * 4096); \
        async16(&Vb[BUF][wid * 1024 + 512], vg + (size_t)(TILE) * 4096 + 512); }

    #define NKLOAD(TILE, N00, N01, N10, N11) { \
        const float* nkt = nkg + (TILE) * 64; \
        N00 = *(const f32x4*)(nkt);      N01 = *(const f32x4*)(nkt + 4); \
        N10 = *(const f32x4*)(nkt + 32); N11 = *(const f32x4*)(nkt + 36); }

    #define HALF(BUF, J, NK0, NK1) { \
        const f16x8 kf0 = *(const f16x8*)(&Kb[BUF][(lg * 64 + (J) * 32 + lm) * 8]); \
        const f16x8 kf1 = *(const f16x8*)(&Kb[BUF][(lg * 64 + (J) * 32 + 16 + lm) * 8]); \
        __builtin_amdgcn_s_setprio(1); \
        const f32x4 SA0 = __builtin_amdgcn_mfma_f32_16x16x32_f16(kf0, qfA, (f32x4){0.f,0.f,0.f,0.f}, 0, 0, 0); \
        const f32x4 SB0 = __builtin_amdgcn_mfma_f32_16x16x32_f16(kf0, qfB, (f32x4){0.f,0.f,0.f,0.f}, 0, 0, 0); \
        const f32x4 SA1 = __builtin_amdgcn_mfma_f32_16x16x32_f16(kf1, qfA, (f32x4){0.f,0.f,0.f,0.f}, 0, 0, 0); \
        const f32x4 SB1 = __builtin_amdgcn_mfma_f32_16x16x32_f16(kf1, qfB, (f32x4){0.f,0.f,0.f,0.f}, 0, 0, 0); \
        __builtin_amdgcn_s_setprio(0); \
        f16x8 paA, paB; \
        _Pragma("unroll") \
        for (int r = 0; r < 4; ++r) { \
            paA[r]     = (_Float16)__builtin_amdgcn_exp2f(__builtin_amdgcn_exp2f(SA0[r] + (nqA + NK0[r]))); \
            paA[4 + r] = (_Float16)__builtin_amdgcn_exp2f(__builtin_amdgcn_exp2f(SA1[r] + (nqA + NK1[r]))); \
            paB[r]     = (_Float16)__builtin_amdgcn_exp2f(__builtin_amdgcn_exp2f(SB0[r] + (nqB + NK0[r]))); \
            paB[4 + r] = (_Float16)__builtin_amdgcn_exp2f(__builtin_amdgcn_exp2f(SB1[r] + (nqB + NK1[r]))); \
        } \
        __builtin_amdgcn_s_setprio(1); \
        _Pragma("unroll") \
        for (int tc = 0; tc < 4; ++tc) { \
            const f16x8 vf = *(const f16x8*)(&Vb[BUF][(((J) * 4 + lg) * 64 + tc * 16 + lm) * 8]); \
            accA[tc] = __builtin_amdgcn_mfma_f32_16x16x32_f16(paA, vf, accA[tc], 0, 0, 0); \
            accB[tc] = __builtin_amdgcn_mfma_f32_16x16x32_f16(paB, vf, accB[tc], 0, 0, 0); \
        } \
        accdA = __builtin_amdgcn_mfma_f32_16x16x32_f16(paA, ones, accdA, 0, 0, 0); \
        accdB = __builtin_amdgcn_mfma_f32_16x16x32_f16(paB, ones, accdB, 0, 0, 0); \
        __builtin_amdgcn_s_setprio(0); }

    ISSUE(0, 0);
    for (int tt = 0; tt < 8; ++tt) {
        const int te = tt * 2;
        {   // even tile -> buf 0
            f32x4 e00, e01, e10, e11;
            NKLOAD(te, e00, e01, e10, e11);
            ISSUE(te + 1, 1);
            asm volatile("s_waitcnt vmcnt(7)" ::: "memory");
            __builtin_amdgcn_s_barrier();
            HALF(0, 0, e00, e01);
            HALF(0, 1, e10, e11);
            __builtin_amdgcn_s_barrier();
        }
        {   // odd tile -> buf 1
            f32x4 o00, o01, o10, o11;
            NKLOAD(te + 1, o00, o01, o10, o11);
            if (tt < 7) {
                ISSUE(te + 2, 0);
                asm volatile("s_waitcnt vmcnt(7)" ::: "memory");
            } else {
                asm volatile("s_waitcnt vmcnt(4)" ::: "memory");
            }
            __builtin_amdgcn_s_barrier();
            HALF(1, 0, o00, o01);
            HALF(1, 1, o10, o11);
            __builtin_amdgcn_s_barrier();
        }
    }

    // ---- store partials: D[query at lg*4+r][channel at lm] ----
    const size_t obA = ((size_t)split * B_ + b) * N_ + qbase;
    if (lm == 0) {
        #pragma unroll
        for (int r = 0; r < 4; ++r) {
            dpart[obA + lg * 4 + r] = accdA[r];
            dpart[obA + 16 + lg * 4 + r] = accdB[r];
        }
    }
    #pragma unroll
    for (int tc = 0; tc < 4; ++tc) {
        #pragma unroll
        for (int r = 0; r < 4; ++r) {
            opart[(obA + lg * 4 + r) * C_ + tc * 16 + lm] = (_Float16)accA[tc][r];
            opart[(obA + 16 + lg * 4 + r) * C_ + tc * 16 + lm] = (_Float16)accB[tc][r];
        }
    }
}

// ---------------- combine kernel: sum partials, divide, add x ----------------
__global__ __launch_bounds__(256) void combine_kernel(
    const float* __restrict__ x,
    const _Float16* __restrict__ opart,
    const float* __restrict__ dpart,
    float* __restrict__ out)
{
    const int gid = blockIdx.x * 256 + threadIdx.x;
    const int c0 = (gid & 7) * 8;
    const int bn = gid >> 3;

    float den = 0.f;
    #pragma unroll
    for (int s = 0; s < SPLIT; ++s) den += dpart[(size_t)s * B_ * N_ + bn];
    const float rden = 1.0f / den;

    float o[8] = {0.f, 0.f, 0.f, 0.f, 0.f, 0.f, 0.f, 0.f};
    #pragma unroll
    for (int s = 0; s < SPLIT; ++s) {
        const f16x8 h = *(const f16x8*)(opart + (((size_t)s * B_ * N_ + bn) * C_ + c0));
        #pragma unroll
        for (int e = 0; e < 8; ++e) o[e] += (float)h[e];
    }

    const size_t base = (size_t)bn * C_ + c0;
    const f32x4 x0 = *(const f32x4*)(x + base);
    const f32x4 x1 = *(const f32x4*)(x + base + 4);
    f32x4 r0, r1;
    #pragma unroll
    for (int e = 0; e < 4; ++e) {
        r0[e] = x0[e] + o[e] * rden;
        r1[e] = x1[e] + o[e + 4] * rden;
    }
    *(f32x4*)(out + base) = r0;
    *(f32x4*)(out + base + 4) = r1;
}

extern "C" void kernel_launch(void* const* d_in, const int* in_sizes, int n_in,
                              void* d_out, int out_size, void* d_ws, size_t ws_size,
                              hipStream_t stream) {
    const float* x   = (const float*)d_in[0];
    const float* Wq  = (const float*)d_in[1];
    const float* bq  = (const float*)d_in[2];
    const float* Wk  = (const float*)d_in[3];
    const float* bk  = (const float*)d_in[4];
    const float* Wv  = (const float*)d_in[5];
    const float* bv  = (const float*)d_in[6];
    const float* sig = (const float*)d_in[7];
    float* out = (float*)d_out;

    char* ws = (char*)d_ws;
    _Float16* qh   = (_Float16*)(ws);                         // 2 MB   [B][N][32]
    _Float16* khf  = (_Float16*)(ws + (2u << 20));            // 2 MB   [B][N/64][4][64][8]
    _Float16* vhf  = (_Float16*)(ws + (4u << 20));            // 4 MB   [B][N/64][2][4][64][8]
    float*   nqs   = (float*)(ws + (8u << 20));               // 128 KB [B][N]
    float*   nkf   = (float*)(ws + (8u << 20) + (128u << 10));// 128 KB [B][N/32][32]
    _Float16* opart = (_Float16*)(ws + (8u << 20) + (256u << 10)); // 16 MB [SPLIT][B][N][64]
    float*   dpart = (float*)(ws + (24u << 20) + (256u << 10));    // 512 KB [SPLIT][B][N]

    proj_kernel<<<B_ * (N_ / 64), 512, 0, stream>>>(x, Wq, bq, Wk, bk, Wv, bv, sig,
                                                    qh, khf, vhf, nqs, nkf);
    attn_kernel<<<B_ * (N_ / QB) * SPLIT, 256, 0, stream>>>(qh, khf, vhf, nqs, nkf,
                                                            opart, dpart);
    combine_kernel<<<(B_ * N_ * 8) / 256, 256, 0, stream>>>(x, opart, dpart, out);
}

// Round 7
// 70.073 us; speedup vs baseline: 1.4080x; 1.1890x over previous
//
#include <hip/hip_runtime.h>
#include <hip/hip_bf16.h>

typedef __attribute__((ext_vector_type(4))) _Float16 f16x4;
typedef __attribute__((ext_vector_type(8))) _Float16 f16x8;
typedef __attribute__((ext_vector_type(4))) float f32x4;

#define B_ 8
#define N_ 4096
#define C_ 64
#define CQ_ 32
#define SPLIT 4
#define KEYS (N_ / SPLIT)
#define MB 64
#define NT (KEYS / MB)   // 16
#define QB 128           // queries per block (4 waves x 32)

#define L2E_ 1.4426950408889634f
#define LOG2L_ 0.5287663729448977f

// minimax cubic for 2^y on [0, 1.443]
#define P0_ 0.9992f
#define P1_ 0.70591f
#define P2_ 0.20093f
#define P3_ 0.094395f

__device__ __forceinline__ void async16(void* lds, const void* gsrc) {
    __builtin_amdgcn_global_load_lds(
        (const __attribute__((address_space(1))) unsigned int*)gsrc,
        (__attribute__((address_space(3))) unsigned int*)lds, 16, 0, 0);
}
__device__ __forceinline__ void async4(void* lds, const void* gsrc) {
    __builtin_amdgcn_global_load_lds(
        (const __attribute__((address_space(1))) unsigned int*)gsrc,
        (__attribute__((address_space(3))) unsigned int*)lds, 4, 0, 0);
}

// ---------------- projection kernel v7: two block types, 256 threads ----------------
// grid 1024: bid<512 -> q/k block (waves: q-lo,q-hi,k-lo,k-hi); else v block (v0..v3).
// Outputs: qh[B][N][32] = q*c1; khf[B][N/64][g:4][key:64][8]; vhf[B][N/64][jg:8][ch:64][8];
//          nqs[B][N] = log2(log2e) - |q|^2*cdL;  nkf[B][N/32][kappa:32] = -|k|^2*cdL.
__global__ __launch_bounds__(256) void proj_kernel(
    const float* __restrict__ x,
    const float* __restrict__ Wq, const float* __restrict__ bq,
    const float* __restrict__ Wk, const float* __restrict__ bk,
    const float* __restrict__ Wv, const float* __restrict__ bv,
    const float* __restrict__ sigp,
    _Float16* __restrict__ qh, _Float16* __restrict__ khf,
    _Float16* __restrict__ vhf,
    float* __restrict__ nqs, float* __restrict__ nkf)
{
    __shared__ float xs[64][64];
    __shared__ float sP[4][64];
    __shared__ _Float16 vtmp[64][76];

    const int t = threadIdx.x;
    const int wid = __builtin_amdgcn_readfirstlane(t >> 6);
    const int l = t & 63;
    const int typeB = (int)(blockIdx.x >> 9);
    const int bid = blockIdx.x & 511;
    const int b = bid >> 6;
    const int tile = bid & 63;
    const int n0 = tile * 64;

    #pragma unroll
    for (int rep = 0; rep < 16; ++rep) {
        const int idx = rep * 256 + t;
        xs[idx >> 6][idx & 63] = x[((size_t)b * C_ + (idx >> 6)) * N_ + n0 + (idx & 63)];
    }
    __syncthreads();

    const float* Wr;
    const float* br;
    if (!typeB) {
        Wr = (wid < 2) ? (Wq + wid * 16 * 64) : (Wk + (wid - 2) * 16 * 64);
        br = (wid < 2) ? (bq + wid * 16) : (bk + (wid - 2) * 16);
    } else {
        Wr = Wv + wid * 16 * 64;
        br = bv + wid * 16;
    }

    float acc[16];
    #pragma unroll
    for (int o = 0; o < 16; ++o) acc[o] = br[o];
    #pragma unroll
    for (int c0 = 0; c0 < 64; c0 += 8) {
        float xc[8];
        #pragma unroll
        for (int dc = 0; dc < 8; ++dc) xc[dc] = xs[c0 + dc][l];
        #pragma unroll
        for (int o = 0; o < 16; ++o) {
            #pragma unroll
            for (int dc = 0; dc < 8; ++dc)
                acc[o] = fmaf(Wr[o * 64 + c0 + dc], xc[dc], acc[o]);
        }
    }

    const float sv = sigp[0];
    const float cdL = 0.7213475204444817f / (sv * sv);  // (log2e/2)/sigma^2
    const float c1 = 2.0f * cdL;
    const int n = n0 + l;

    if (!typeB) {
        float s = 0.f;
        #pragma unroll
        for (int o = 0; o < 16; ++o) s = fmaf(acc[o], acc[o], s);
        sP[wid][l] = s;
        if (wid < 2) {          // q: scale by c1, row store
            _Float16* row = qh + ((size_t)b * N_ + n) * CQ_ + wid * 16;
            #pragma unroll
            for (int j = 0; j < 2; ++j) {
                f16x8 h;
                #pragma unroll
                for (int e = 0; e < 8; ++e) h[e] = (_Float16)(acc[j * 8 + e] * c1);
                *(f16x8*)(row + j * 8) = h;
            }
        } else {                // k: granule-major tile store
            const size_t tbase = ((size_t)b * (N_ / 64) + tile) * 4;
            #pragma unroll
            for (int gi = 0; gi < 2; ++gi) {
                const int g = (wid - 2) * 2 + gi;
                f16x8 h;
                #pragma unroll
                for (int e = 0; e < 8; ++e) h[e] = (_Float16)acc[gi * 8 + e];
                *(f16x8*)(khf + (tbase + g) * 512 + l * 8) = h;
            }
        }
        __syncthreads();
        if (t < 64) {
            nqs[(size_t)b * N_ + n0 + t] = LOG2L_ - (sP[0][t] + sP[1][t]) * cdL;
        } else if (t < 128) {
            const int kk = t - 64;
            const int kap = (((kk & 15) >> 2) << 3) + (kk & 3) + (((kk >> 4) & 1) << 2);
            nkf[((size_t)b * (N_ / 32) + ((n0 + kk) >> 5)) * 32 + kap] =
                -(sP[2][kk] + sP[3][kk]) * cdL;
        }
    } else {
        #pragma unroll
        for (int o = 0; o < 16; ++o) vtmp[wid * 16 + o][l] = (_Float16)acc[o];
        __syncthreads();
        #pragma unroll
        for (int p = 0; p < 2; ++p) {
            const int jg = (t >> 6) + p * 4;       // 0..7 = j*4+g
            const int ch = t & 63;
            const int p0 = (jg >> 2) * 32 + (jg & 3) * 4;
            const f16x4 a0 = *(const f16x4*)(&vtmp[ch][p0]);
            const f16x4 a1 = *(const f16x4*)(&vtmp[ch][p0 + 16]);
            f16x8 hv;
            #pragma unroll
            for (int e = 0; e < 4; ++e) { hv[e] = a0[e]; hv[4 + e] = a1[e]; }
            *(f16x8*)(vhf + ((size_t)b * (N_ / 64) + tile) * 4096 + (jg * 64 + ch) * 8) = hv;
        }
    }
}

// ---------------- fused RBF-attention v7 ----------------
// Tri-buffered glds staging (K,V,nk), 1 barrier + vmcnt(4) per tile.
// QK MFMA C-operand = nk; nq folded into per-lane Horner coefficients.
__global__ __launch_bounds__(256, 4) void attn_kernel(
    const _Float16* __restrict__ qh,
    const _Float16* __restrict__ khf,
    const _Float16* __restrict__ vhf,
    const float* __restrict__ nqs,
    const float* __restrict__ nkf,
    _Float16* __restrict__ opart,
    float* __restrict__ dpart)
{
    __shared__ __align__(16) _Float16 Kb[3][2048];   // [g:4][key:64][8]
    __shared__ __align__(16) _Float16 Vb[3][4096];   // [j:2][g:4][ch:64][8]
    __shared__ __align__(16) float sNk[3][4][64];    // per-wave private copy

    const int t = threadIdx.x;
    const int wid = t >> 6;
    const int l = t & 63;
    const int lg = l >> 4;
    const int lm = l & 15;

    const int split = blockIdx.x & (SPLIT - 1);
    const int qblk = (blockIdx.x >> 2) & 31;
    const int b = blockIdx.x >> 7;
    const int qbase = qblk * QB + wid * 32;
    const int k0 = split * KEYS;
    const size_t bN = (size_t)b * N_;

    const f16x8 qfA = *(const f16x8*)(qh + (bN + qbase + lm) * CQ_ + 8 * lg);
    const f16x8 qfB = *(const f16x8*)(qh + (bN + qbase + 16 + lm) * CQ_ + 8 * lg);
    const float eA = __builtin_amdgcn_exp2f(nqs[bN + qbase + lm]);
    const float eB = __builtin_amdgcn_exp2f(nqs[bN + qbase + 16 + lm]);
    const float C1A = P1_ * eA, C2A = P2_ * eA * eA, C3A = P3_ * eA * eA * eA;
    const float C1B = P1_ * eB, C2B = P2_ * eB * eB, C3B = P3_ * eB * eB * eB;

    const _Float16* kg = khf + ((size_t)b * (N_ / 64) + (k0 >> 6)) * 2048 + wid * 512 + l * 8;
    const _Float16* vg = vhf + ((size_t)b * (N_ / 64) + (k0 >> 6)) * 4096 + wid * 1024 + l * 8;
    const float* nkg = nkf + bN + k0 + l;

    f32x4 accA[4], accB[4], accdA, accdB;
    #pragma unroll
    for (int i = 0; i < 4; ++i) {
        accA[i] = (f32x4){0.f, 0.f, 0.f, 0.f};
        accB[i] = (f32x4){0.f, 0.f, 0.f, 0.f};
    }
    accdA = (f32x4){0.f, 0.f, 0.f, 0.f};
    accdB = (f32x4){0.f, 0.f, 0.f, 0.f};
    f16x8 ones;
    #pragma unroll
    for (int e = 0; e < 8; ++e) ones[e] = (_Float16)1.0f;

    #define ISSUE(TILE, BUF) { \
        async16(&Kb[BUF][wid * 512],        kg + (size_t)(TILE) * 2048); \
        async16(&Vb[BUF][wid * 1024],       vg + (size_t)(TILE) * 4096); \
        async16(&Vb[BUF][wid * 1024 + 512], vg + (size_t)(TILE) * 4096 + 512); \
        async4 (&sNk[BUF][wid][0],          nkg + (TILE) * 64); }

    #define HALF(BUF, J) { \
        const f32x4 NK0 = *(const f32x4*)(&sNk[BUF][wid][(J) * 32 + lg * 8]); \
        const f32x4 NK1 = *(const f32x4*)(&sNk[BUF][wid][(J) * 32 + lg * 8 + 4]); \
        const f16x8 kf0 = *(const f16x8*)(&Kb[BUF][(lg * 64 + (J) * 32 + lm) * 8]); \
        const f16x8 kf1 = *(const f16x8*)(&Kb[BUF][(lg * 64 + (J) * 32 + 16 + lm) * 8]); \
        __builtin_amdgcn_s_setprio(1); \
        const f32x4 SA0 = __builtin_amdgcn_mfma_f32_16x16x32_f16(kf0, qfA, NK0, 0, 0, 0); \
        const f32x4 SB0 = __builtin_amdgcn_mfma_f32_16x16x32_f16(kf0, qfB, NK0, 0, 0, 0); \
        const f32x4 SA1 = __builtin_amdgcn_mfma_f32_16x16x32_f16(kf1, qfA, NK1, 0, 0, 0); \
        const f32x4 SB1 = __builtin_amdgcn_mfma_f32_16x16x32_f16(kf1, qfB, NK1, 0, 0, 0); \
        __builtin_amdgcn_s_setprio(0); \
        f16x8 paA, paB; \
        _Pragma("unroll") \
        for (int r = 0; r < 4; ++r) { \
            const float yA0 = __builtin_amdgcn_exp2f(SA0[r]); \
            const float yA1 = __builtin_amdgcn_exp2f(SA1[r]); \
            const float yB0 = __builtin_amdgcn_exp2f(SB0[r]); \
            const float yB1 = __builtin_amdgcn_exp2f(SB1[r]); \
            paA[r]     = (_Float16)fmaf(fmaf(fmaf(C3A, yA0, C2A), yA0, C1A), yA0, P0_); \
            paA[4 + r] = (_Float16)fmaf(fmaf(fmaf(C3A, yA1, C2A), yA1, C1A), yA1, P0_); \
            paB[r]     = (_Float16)fmaf(fmaf(fmaf(C3B, yB0, C2B), yB0, C1B), yB0, P0_); \
            paB[4 + r] = (_Float16)fmaf(fmaf(fmaf(C3B, yB1, C2B), yB1, C1B), yB1, P0_); \
        } \
        __builtin_amdgcn_s_setprio(1); \
        _Pragma("unroll") \
        for (int tc = 0; tc < 4; ++tc) { \
            const f16x8 vf = *(const f16x8*)(&Vb[BUF][(((J) * 4 + lg) * 64 + tc * 16 + lm) * 8]); \
            accA[tc] = __builtin_amdgcn_mfma_f32_16x16x32_f16(paA, vf, accA[tc], 0, 0, 0); \
            accB[tc] = __builtin_amdgcn_mfma_f32_16x16x32_f16(paB, vf, accB[tc], 0, 0, 0); \
        } \
        accdA = __builtin_amdgcn_mfma_f32_16x16x32_f16(paA, ones, accdA, 0, 0, 0); \
        accdB = __builtin_amdgcn_mfma_f32_16x16x32_f16(paB, ones, accdB, 0, 0, 0); \
        __builtin_amdgcn_s_setprio(0); }

    ISSUE(0, 0);
    #pragma unroll
    for (int tt = 0; tt < NT; ++tt) {
        const int bufc = tt % 3;
        if (tt + 1 < NT) ISSUE(tt + 1, (tt + 1) % 3);
        if (tt == 0 || tt + 1 >= NT)
            asm volatile("s_waitcnt vmcnt(0)" ::: "memory");
        else
            asm volatile("s_waitcnt vmcnt(4)" ::: "memory");
        asm volatile("s_barrier" ::: "memory");
        HALF(bufc, 0);
        HALF(bufc, 1);
    }

    // ---- store partials: D[query at lg*4+r][channel at lm] ----
    const size_t obA = ((size_t)split * B_ + b) * N_ + qbase;
    if (lm == 0) {
        #pragma unroll
        for (int r = 0; r < 4; ++r) {
            dpart[obA + lg * 4 + r] = accdA[r];
            dpart[obA + 16 + lg * 4 + r] = accdB[r];
        }
    }
    #pragma unroll
    for (int tc = 0; tc < 4; ++tc) {
        #pragma unroll
        for (int r = 0; r < 4; ++r) {
            opart[(obA + lg * 4 + r) * C_ + tc * 16 + lm] = (_Float16)accA[tc][r];
            opart[(obA + 16 + lg * 4 + r) * C_ + tc * 16 + lm] = (_Float16)accB[tc][r];
        }
    }
}

// ---------------- combine kernel: sum partials, divide, add x ----------------
__global__ __launch_bounds__(256) void combine_kernel(
    const float* __restrict__ x,
    const _Float16* __restrict__ opart,
    const float* __restrict__ dpart,
    float* __restrict__ out)
{
    const int gid = blockIdx.x * 256 + threadIdx.x;
    const int c0 = (gid & 7) * 8;
    const int bn = gid >> 3;

    float den = 0.f;
    #pragma unroll
    for (int s = 0; s < SPLIT; ++s) den += dpart[(size_t)s * B_ * N_ + bn];
    const float rden = 1.0f / den;

    float o[8] = {0.f, 0.f, 0.f, 0.f, 0.f, 0.f, 0.f, 0.f};
    #pragma unroll
    for (int s = 0; s < SPLIT; ++s) {
        const f16x8 h = *(const f16x8*)(opart + (((size_t)s * B_ * N_ + bn) * C_ + c0));
        #pragma unroll
        for (int e = 0; e < 8; ++e) o[e] += (float)h[e];
    }

    const size_t base = (size_t)bn * C_ + c0;
    const f32x4 x0 = *(const f32x4*)(x + base);
    const f32x4 x1 = *(const f32x4*)(x + base + 4);
    f32x4 r0, r1;
    #pragma unroll
    for (int e = 0; e < 4; ++e) {
        r0[e] = x0[e] + o[e] * rden;
        r1[e] = x1[e] + o[e + 4] * rden;
    }
    *(f32x4*)(out + base) = r0;
    *(f32x4*)(out + base + 4) = r1;
}

extern "C" void kernel_launch(void* const* d_in, const int* in_sizes, int n_in,
                              void* d_out, int out_size, void* d_ws, size_t ws_size,
                              hipStream_t stream) {
    const float* x   = (const float*)d_in[0];
    const float* Wq  = (const float*)d_in[1];
    const float* bq  = (const float*)d_in[2];
    const float* Wk  = (const float*)d_in[3];
    const float* bk  = (const float*)d_in[4];
    const float* Wv  = (const float*)d_in[5];
    const float* bv  = (const float*)d_in[6];
    const float* sig = (const float*)d_in[7];
    float* out = (float*)d_out;

    char* ws = (char*)d_ws;
    _Float16* qh   = (_Float16*)(ws);                         // 2 MB   [B][N][32]
    _Float16* khf  = (_Float16*)(ws + (2u << 20));            // 2 MB   [B][N/64][4][64][8]
    _Float16* vhf  = (_Float16*)(ws + (4u << 20));            // 4 MB   [B][N/64][8][64][8]
    float*   nqs   = (float*)(ws + (8u << 20));               // 128 KB [B][N]
    float*   nkf   = (float*)(ws + (8u << 20) + (128u << 10));// 128 KB [B][N/32][32]
    _Float16* opart = (_Float16*)(ws + (8u << 20) + (256u << 10)); // 16 MB [SPLIT][B][N][64]
    float*   dpart = (float*)(ws + (24u << 20) + (256u << 10));    // 512 KB [SPLIT][B][N]

    proj_kernel<<<1024, 256, 0, stream>>>(x, Wq, bq, Wk, bk, Wv, bv, sig,
                                          qh, khf, vhf, nqs, nkf);
    attn_kernel<<<B_ * (N_ / QB) * SPLIT, 256, 0, stream>>>(qh, khf, vhf, nqs, nkf,
                                                            opart, dpart);
    combine_kernel<<<(B_ * N_ * 8) / 256, 256, 0, stream>>>(x, opart, dpart, out);
}